// Round 4
// baseline (61.165 us; speedup 1.0000x reference)
//
#include <hip/hip_runtime.h>
#include <cstdint>
#include <cstddef>

#define PD 1024          // feature dim D (fixed by the problem)
#define PER_IMG 256      // proposals per image
#define TEMP_INV 5.0f    // 1 / TEMPERATURE (0.2)
#define IOU_THRES 0.4f
#define SPLIT 8          // blocks per image
#define RPB (PER_IMG / SPLIT)   // rows per block  = 32
#define RW  (RPB / 4)           // rows per wave   = 8
#define K4  4            // K scales (problem-fixed)

typedef float f32x4 __attribute__((ext_vector_type(4)));

__device__ inline f32x4 ntload4(const float* p) {
    return __builtin_nontemporal_load(reinterpret_cast<const f32x4*>(p));
}

// ---------------------------------------------------------------------------
// Single fused kernel (plus a 4-byte memset node for the completion counter).
//
// Phase A (all blocks): block (b,s) normalizes rows [s*RPB,(s+1)*RPB) of image
//   b, accumulates masked row-sums in registers, dots them per-wave against
//   all K crop vectors (L2-hot), and writes 2K+1(+K) scalars to workspace.
// Phase B (last block to finish, detected via device-scope atomic counter):
//   combines the 8 split partials per (k,b), softplus, sum over b, min over k.
// Cross-XCD visibility: __threadfence() release before the atomic (writers'
// stores drained by the pre-barrier vmcnt(0), flushed by buffer_wbl2 sc1),
// __threadfence() acquire in every thread of the last block before reading.
// ---------------------------------------------------------------------------
__global__ __launch_bounds__(256) void k1_fused(
    const float* __restrict__ box, const float* __restrict__ ious,
    const float* __restrict__ crop,
    float* __restrict__ wsP, float* __restrict__ wsA,
    float* __restrict__ wsZ, float* __restrict__ wsCnt,
    unsigned int* __restrict__ counter,
    float* __restrict__ out, int B, int K)
{
    const int b    = blockIdx.x / SPLIT;
    const int s    = blockIdx.x % SPLIT;
    const int t    = threadIdx.x;
    const int lane = t & 63;
    const int wv   = t >> 6;                // 0..3
    const int row0 = s * RPB + wv * RW;     // wave's first row (contiguous)
    const int nblk = B * SPLIT;

    __shared__ float ldsD[4][2 * K4];
    __shared__ float ldsZ[K4];
    __shared__ int   cntLds;
    __shared__ int   lastFlag;
    __shared__ float spl[512];              // K*B <= 512
    __shared__ float red[K4];

    // ---------------- Phase A: stream + normalize + accumulate -------------
    float accP[16], accA[16];
#pragma unroll
    for (int i = 0; i < 16; ++i) { accP[i] = 0.f; accA[i] = 0.f; }
    int cnt = 0;

    const size_t growBase = (size_t)b * PER_IMG + row0;
    const float* rp = box + growBase * PD;

#pragma unroll 1
    for (int it = 0; it < RW; it += 4) {
        f32x4 v[4][4];
#pragma unroll
        for (int r = 0; r < 4; ++r)
#pragma unroll
            for (int j = 0; j < 4; ++j)
                v[r][j] = ntload4(rp + (size_t)(it + r) * PD + (j * 64 + lane) * 4);

        float iou[4];
#pragma unroll
        for (int r = 0; r < 4; ++r) iou[r] = ious[growBase + it + r];

        float ss[4];
#pragma unroll
        for (int r = 0; r < 4; ++r) {
            float acc = 0.f;
#pragma unroll
            for (int j = 0; j < 4; ++j)
                acc += v[r][j][0] * v[r][j][0] + v[r][j][1] * v[r][j][1]
                     + v[r][j][2] * v[r][j][2] + v[r][j][3] * v[r][j][3];
            ss[r] = acc;
        }
#pragma unroll
        for (int off = 32; off >= 1; off >>= 1) {
#pragma unroll
            for (int r = 0; r < 4; ++r)
                ss[r] += __shfl_xor(ss[r], off, 64);
        }

#pragma unroll
        for (int r = 0; r < 4; ++r) {
            const float inv = 1.0f / fmaxf(sqrtf(ss[r]), 1e-12f);
            const bool pos = iou[r] >= IOU_THRES;
            if (pos && lane == 0) ++cnt;
            const float pm = pos ? inv : 0.f;
#pragma unroll
            for (int j = 0; j < 4; ++j) {
#pragma unroll
                for (int c = 0; c < 4; ++c) {
                    accA[j * 4 + c] += v[r][j][c] * inv;
                    accP[j * 4 + c] += v[r][j][c] * pm;
                }
            }
        }
    }

    // ---------------- per-wave register dots against all K z-vectors -------
    if (t == 0) { cntLds = 0; lastFlag = 0; }
    __syncthreads();
    if (lane == 0 && cnt) atomicAdd(&cntLds, cnt);

    float dP[K4], dA[K4], zz[K4];
#pragma unroll
    for (int k = 0; k < K4; ++k) {
        const float* zp = crop + ((size_t)k * B + b) * PD;
        float p = 0.f, a = 0.f, z2 = 0.f;
#pragma unroll
        for (int j = 0; j < 4; ++j) {
            const int d = (j * 64 + lane) * 4;
            const f32x4 z = *reinterpret_cast<const f32x4*>(zp + d);
#pragma unroll
            for (int c = 0; c < 4; ++c) {
                p  += accP[j * 4 + c] * z[c];
                a  += accA[j * 4 + c] * z[c];
                z2 += z[c] * z[c];
            }
        }
        dP[k] = p; dA[k] = a; zz[k] = z2;
    }
#pragma unroll
    for (int off = 32; off >= 1; off >>= 1) {
#pragma unroll
        for (int k = 0; k < K4; ++k) {
            dP[k] += __shfl_xor(dP[k], off, 64);
            dA[k] += __shfl_xor(dA[k], off, 64);
            zz[k] += __shfl_xor(zz[k], off, 64);
        }
    }
    if (lane == 0) {
#pragma unroll
        for (int k = 0; k < K4; ++k) {
            ldsD[wv][k]      = dP[k];
            ldsD[wv][K4 + k] = dA[k];
        }
        if (wv == 0)
#pragma unroll
            for (int k = 0; k < K4; ++k) ldsZ[k] = zz[k];
    }
    __syncthreads();

    // ---------------- write 2K+1(+K) scalars to workspace ------------------
    if (t < 2 * K4) {
        const float v = ldsD[0][t] + ldsD[1][t] + ldsD[2][t] + ldsD[3][t];
        const int k = (t < K4) ? t : (t - K4);
        const size_t kb = (size_t)k * B + b;
        if (t < K4) wsP[kb * SPLIT + s] = v;
        else        wsA[kb * SPLIT + s] = v;
    }
    if (s == 0 && t >= 8 && t < 8 + K4) wsZ[(size_t)(t - 8) * B + b] = ldsZ[t - 8];
    if (t == 12) wsCnt[b * SPLIT + s] = (float)cntLds;
    __syncthreads();                 // drain stores (vmcnt(0) before barrier)

    // ---------------- completion count (device scope) ----------------------
    if (t == 0) {
        __threadfence();             // release: flush this XCD's L2
        const unsigned old = atomicAdd(counter, 1u);
        if (old == (unsigned)(nblk - 1)) lastFlag = 1;
    }
    __syncthreads();
    if (!lastFlag) return;

    // ---------------- Phase B: final reduction (last block only) -----------
    __threadfence();                 // acquire: invalidate L1 + this XCD's L2

    const int KB = K4 * B;
    for (int pair = t; pair < KB; pair += 256) {
        const int bb = pair & (B - 1);
        float P = 0.f, A = 0.f, C = 0.f;
#pragma unroll
        for (int sp = 0; sp < SPLIT; ++sp) {
            P += wsP[(size_t)pair * SPLIT + sp];
            A += wsA[(size_t)pair * SPLIT + sp];
            C += wsCnt[bb * SPLIT + sp];
        }
        const float invz = 1.0f / fmaxf(sqrtf(wsZ[pair]), 1e-12f);
        const float simP = -(P * invz) / C;
        const float simN = -((A - P) * invz) / ((float)PER_IMG - C);
        const float x = (simN - simP) * TEMP_INV;
        spl[pair] = fmaxf(x, 0.f) + log1pf(expf(-fabsf(x)));  // softplus
    }
    __syncthreads();

    if (wv < K4) {
        float v = 0.f;
        for (int bb = lane; bb < B; bb += 64) v += spl[wv * B + bb];
#pragma unroll
        for (int off = 32; off >= 1; off >>= 1)
            v += __shfl_xor(v, off, 64);
        if (lane == 0) red[wv] = v;
    }
    __syncthreads();
    if (t == 0) {
        float m = red[0];
        for (int k = 1; k < K4; ++k) m = fminf(m, red[k]);
        out[0] = m / (float)B;
    }
}

// ---------------------------------------------------------------------------
extern "C" void kernel_launch(void* const* d_in, const int* in_sizes, int n_in,
                              void* d_out, int out_size, void* d_ws, size_t ws_size,
                              hipStream_t stream)
{
    const float* box  = (const float*)d_in[0];   // [N, D] f32
    const float* crop = (const float*)d_in[1];   // [K, B, D] f32
    const float* ious = (const float*)d_in[3];   // [N] f32

    const int N = in_sizes[3];
    const int B = N / PER_IMG;                   // 128
    const int D = in_sizes[0] / N;               // 1024 (layout fixed = PD)
    const int K = in_sizes[1] / (B * D);         // 4 (problem-fixed = K4)

    char* w = (char*)d_ws;
    float* wsP   = (float*)w;  w += (size_t)K4 * B * SPLIT * sizeof(float);
    float* wsA   = (float*)w;  w += (size_t)K4 * B * SPLIT * sizeof(float);
    float* wsZ   = (float*)w;  w += (size_t)K4 * B * sizeof(float);
    float* wsCnt = (float*)w;  w += (size_t)B * SPLIT * sizeof(float);
    unsigned int* counter = (unsigned int*)w;

    hipMemsetAsync(counter, 0, sizeof(unsigned int), stream);
    hipLaunchKernelGGL(k1_fused, dim3(B * SPLIT), dim3(256), 0, stream,
                       box, ious, crop, wsP, wsA, wsZ, wsCnt, counter,
                       (float*)d_out, B, K);
}

// Round 5
// 48.496 us; speedup vs baseline: 1.2612x; 1.2612x over previous
//
#include <hip/hip_runtime.h>
#include <cstdint>
#include <cstddef>

#define PD 1024          // feature dim D (fixed by the problem)
#define PER_IMG 256      // proposals per image
#define TEMP_INV 5.0f    // 1 / TEMPERATURE (0.2)
#define IOU_THRES 0.4f
#define SPLIT 8          // blocks per image
#define RPB (PER_IMG / SPLIT)   // rows per block  = 32
#define RW  (RPB / 4)           // rows per wave   = 8
#define K4  4            // K scales (problem-fixed)

typedef float f32x4 __attribute__((ext_vector_type(4)));

__device__ inline f32x4 ntload4(const float* p) {
    return __builtin_nontemporal_load(reinterpret_cast<const f32x4*>(p));
}

// agent-scope coherent scalar store/load (sc1 — completes at the device
// coherence point; no L2 flush needed, bypasses stale per-XCD L2 copies)
__device__ inline void agstore(float* p, float v) {
    __hip_atomic_store(p, v, __ATOMIC_RELAXED, __HIP_MEMORY_SCOPE_AGENT);
}
__device__ inline float agload(const float* p) {
    return __hip_atomic_load(p, __ATOMIC_RELAXED, __HIP_MEMORY_SCOPE_AGENT);
}

// ---------------------------------------------------------------------------
// Single fused kernel (plus a 4-byte memset node for the completion counter).
// Phase A (all blocks): block (b,s) normalizes rows [s*RPB,(s+1)*RPB) of
//   image b, accumulates masked row-sums in registers, dots them per-wave
//   against all K crop vectors (L2-hot), publishes 13 scalars via sc1 stores.
// Handoff: wave-0 issues all 13 stores; t0 waits vmcnt(0) (its wave's stores)
//   then relaxed agent-scope fetch_add on the counter. NO buffer_wbl2 — the
//   R4 lesson: per-block release fences (1024 x L2 writeback) cost ~30 us.
// Phase B (last block): sc1-loads all partials, softplus, sum_b, min_k.
// ---------------------------------------------------------------------------
__global__ __launch_bounds__(256) void k1_fused(
    const float* __restrict__ box, const float* __restrict__ ious,
    const float* __restrict__ crop,
    float* __restrict__ wsP, float* __restrict__ wsA,
    float* __restrict__ wsZ, float* __restrict__ wsCnt,
    unsigned int* __restrict__ counter,
    float* __restrict__ out, int B, int K)
{
    const int b    = blockIdx.x / SPLIT;
    const int s    = blockIdx.x % SPLIT;
    const int t    = threadIdx.x;
    const int lane = t & 63;
    const int wv   = t >> 6;                // 0..3
    const int row0 = s * RPB + wv * RW;     // wave's first row (contiguous)
    const int nblk = B * SPLIT;

    __shared__ float ldsD[4][2 * K4];
    __shared__ float ldsZ[K4];
    __shared__ int   cntLds;
    __shared__ int   lastFlag;
    __shared__ float spl[512];              // K*B <= 512
    __shared__ float red[K4];

    // ---------------- Phase A: stream + normalize + accumulate -------------
    float accP[16], accA[16];
#pragma unroll
    for (int i = 0; i < 16; ++i) { accP[i] = 0.f; accA[i] = 0.f; }
    int cnt = 0;

    const size_t growBase = (size_t)b * PER_IMG + row0;
    const float* rp = box + growBase * PD;

#pragma unroll 1
    for (int it = 0; it < RW; it += 4) {
        f32x4 v[4][4];
#pragma unroll
        for (int r = 0; r < 4; ++r)
#pragma unroll
            for (int j = 0; j < 4; ++j)
                v[r][j] = ntload4(rp + (size_t)(it + r) * PD + (j * 64 + lane) * 4);

        float iou[4];
#pragma unroll
        for (int r = 0; r < 4; ++r) iou[r] = ious[growBase + it + r];

        float ss[4];
#pragma unroll
        for (int r = 0; r < 4; ++r) {
            float acc = 0.f;
#pragma unroll
            for (int j = 0; j < 4; ++j)
                acc += v[r][j][0] * v[r][j][0] + v[r][j][1] * v[r][j][1]
                     + v[r][j][2] * v[r][j][2] + v[r][j][3] * v[r][j][3];
            ss[r] = acc;
        }
#pragma unroll
        for (int off = 32; off >= 1; off >>= 1) {
#pragma unroll
            for (int r = 0; r < 4; ++r)
                ss[r] += __shfl_xor(ss[r], off, 64);
        }

#pragma unroll
        for (int r = 0; r < 4; ++r) {
            const float inv = 1.0f / fmaxf(sqrtf(ss[r]), 1e-12f);
            const bool pos = iou[r] >= IOU_THRES;
            if (pos && lane == 0) ++cnt;
            const float pm = pos ? inv : 0.f;
#pragma unroll
            for (int j = 0; j < 4; ++j) {
#pragma unroll
                for (int c = 0; c < 4; ++c) {
                    accA[j * 4 + c] += v[r][j][c] * inv;
                    accP[j * 4 + c] += v[r][j][c] * pm;
                }
            }
        }
    }

    // ---------------- per-wave register dots against all K z-vectors -------
    if (t == 0) { cntLds = 0; lastFlag = 0; }
    __syncthreads();
    if (lane == 0 && cnt) atomicAdd(&cntLds, cnt);

    float dP[K4], dA[K4], zz[K4];
#pragma unroll
    for (int k = 0; k < K4; ++k) {
        const float* zp = crop + ((size_t)k * B + b) * PD;
        float p = 0.f, a = 0.f, z2 = 0.f;
#pragma unroll
        for (int j = 0; j < 4; ++j) {
            const int d = (j * 64 + lane) * 4;
            const f32x4 z = *reinterpret_cast<const f32x4*>(zp + d);
#pragma unroll
            for (int c = 0; c < 4; ++c) {
                p  += accP[j * 4 + c] * z[c];
                a  += accA[j * 4 + c] * z[c];
                z2 += z[c] * z[c];
            }
        }
        dP[k] = p; dA[k] = a; zz[k] = z2;
    }
#pragma unroll
    for (int off = 32; off >= 1; off >>= 1) {
#pragma unroll
        for (int k = 0; k < K4; ++k) {
            dP[k] += __shfl_xor(dP[k], off, 64);
            dA[k] += __shfl_xor(dA[k], off, 64);
            zz[k] += __shfl_xor(zz[k], off, 64);
        }
    }
    if (lane == 0) {
#pragma unroll
        for (int k = 0; k < K4; ++k) {
            ldsD[wv][k]      = dP[k];
            ldsD[wv][K4 + k] = dA[k];
        }
        if (wv == 0)
#pragma unroll
            for (int k = 0; k < K4; ++k) ldsZ[k] = zz[k];
    }
    __syncthreads();

    // -------- publish 13 scalars (all issued by wave 0, sc1 stores) --------
    if (t < 2 * K4) {
        const float v = ldsD[0][t] + ldsD[1][t] + ldsD[2][t] + ldsD[3][t];
        const int k = (t < K4) ? t : (t - K4);
        const size_t kb = (size_t)k * B + b;
        agstore((t < K4) ? &wsP[kb * SPLIT + s] : &wsA[kb * SPLIT + s], v);
    }
    if (s == 0 && t >= 8 && t < 8 + K4)
        agstore(&wsZ[(size_t)(t - 8) * B + b], ldsZ[t - 8]);
    if (t == 12) agstore(&wsCnt[b * SPLIT + s], (float)cntLds);

    // -------- completion count: wait own wave's stores, then relaxed add ---
    if (t == 0) {
        asm volatile("s_waitcnt vmcnt(0)" ::: "memory");
        const unsigned old = __hip_atomic_fetch_add(
            counter, 1u, __ATOMIC_RELAXED, __HIP_MEMORY_SCOPE_AGENT);
        if (old == (unsigned)(nblk - 1)) lastFlag = 1;
    }
    __syncthreads();
    if (!lastFlag) return;

    // ---------------- Phase B: final reduction (last block only) -----------
    const int KB = K4 * B;
    for (int pair = t; pair < KB; pair += 256) {
        const int bb = pair & (B - 1);
        float P = 0.f, A = 0.f, C = 0.f;
#pragma unroll
        for (int sp = 0; sp < SPLIT; ++sp) {
            P += agload(&wsP[(size_t)pair * SPLIT + sp]);
            A += agload(&wsA[(size_t)pair * SPLIT + sp]);
            C += agload(&wsCnt[bb * SPLIT + sp]);
        }
        const float invz = 1.0f / fmaxf(sqrtf(agload(&wsZ[pair])), 1e-12f);
        const float simP = -(P * invz) / C;
        const float simN = -((A - P) * invz) / ((float)PER_IMG - C);
        const float x = (simN - simP) * TEMP_INV;
        spl[pair] = fmaxf(x, 0.f) + log1pf(expf(-fabsf(x)));  // softplus
    }
    __syncthreads();

    if (wv < K4) {
        float v = 0.f;
        for (int bb = lane; bb < B; bb += 64) v += spl[wv * B + bb];
#pragma unroll
        for (int off = 32; off >= 1; off >>= 1)
            v += __shfl_xor(v, off, 64);
        if (lane == 0) red[wv] = v;
    }
    __syncthreads();
    if (t == 0) {
        float m = red[0];
        for (int k = 1; k < K4; ++k) m = fminf(m, red[k]);
        out[0] = m / (float)B;
    }
}

// ---------------------------------------------------------------------------
extern "C" void kernel_launch(void* const* d_in, const int* in_sizes, int n_in,
                              void* d_out, int out_size, void* d_ws, size_t ws_size,
                              hipStream_t stream)
{
    const float* box  = (const float*)d_in[0];   // [N, D] f32
    const float* crop = (const float*)d_in[1];   // [K, B, D] f32
    const float* ious = (const float*)d_in[3];   // [N] f32

    const int N = in_sizes[3];
    const int B = N / PER_IMG;                   // 128
    const int D = in_sizes[0] / N;               // 1024 (layout fixed = PD)
    const int K = in_sizes[1] / (B * D);         // 4 (problem-fixed = K4)

    char* w = (char*)d_ws;
    float* wsP   = (float*)w;  w += (size_t)K4 * B * SPLIT * sizeof(float);
    float* wsA   = (float*)w;  w += (size_t)K4 * B * SPLIT * sizeof(float);
    float* wsZ   = (float*)w;  w += (size_t)K4 * B * sizeof(float);
    float* wsCnt = (float*)w;  w += (size_t)B * SPLIT * sizeof(float);
    unsigned int* counter = (unsigned int*)w;

    hipMemsetAsync(counter, 0, sizeof(unsigned int), stream);
    hipLaunchKernelGGL(k1_fused, dim3(B * SPLIT), dim3(256), 0, stream,
                       box, ious, crop, wsP, wsA, wsZ, wsCnt, counter,
                       (float*)d_out, B, K);
}

// Round 6
// 47.334 us; speedup vs baseline: 1.2922x; 1.0245x over previous
//
#include <hip/hip_runtime.h>
#include <cstdint>
#include <cstddef>

#define PD 1024          // feature dim D (fixed by the problem)
#define PER_IMG 256      // proposals per image
#define TEMP_INV 5.0f    // 1 / TEMPERATURE (0.2)
#define IOU_THRES 0.4f
#define SPLIT 8          // blocks per image
#define RPB (PER_IMG / SPLIT)   // rows per block  = 32
#define RW  (RPB / 4)           // rows per wave   = 8
#define K4  4            // K scales (problem-fixed)

typedef float f32x4 __attribute__((ext_vector_type(4)));

__device__ inline f32x4 ntload4(const float* p) {
    return __builtin_nontemporal_load(reinterpret_cast<const f32x4*>(p));
}

// agent-scope coherent scalar store/load (sc1): completes at the device
// coherence point; no L2 writeback needed (R4 lesson: per-block
// __threadfence => 1024x buffer_wbl2 cost ~30 us).
__device__ inline void agstore(float* p, float v) {
    __hip_atomic_store(p, v, __ATOMIC_RELAXED, __HIP_MEMORY_SCOPE_AGENT);
}
__device__ inline float agload(const float* p) {
    return __hip_atomic_load(p, __ATOMIC_RELAXED, __HIP_MEMORY_SCOPE_AGENT);
}

// ---------------------------------------------------------------------------
// Init kernel: zero the completion counter (compute-queue node; replaces the
// hipMemsetAsync fill-blit, removing it as a variable).
// ---------------------------------------------------------------------------
__global__ void k0_init(unsigned int* __restrict__ counter) {
    if (threadIdx.x == 0) *counter = 0u;
}

// ---------------------------------------------------------------------------
// Fused kernel. Phase A identical to R3's k1 (including the low-VGPR LDS
// quadrant-combine epilogue — R4/R5's per-wave register dots are the prime
// suspect for an occupancy regression in the streaming phase). Publishes 13
// scalars per block via sc1 stores; the publish barrier's per-wave implicit
// s_waitcnt vmcnt(0) drains them; t0 then does a relaxed agent-scope
// fetch_add. Last block runs the final reduction (phase B).
// ---------------------------------------------------------------------------
__global__ __launch_bounds__(256) void k1_fused(
    const float* __restrict__ box, const float* __restrict__ ious,
    const float* __restrict__ crop,
    float* __restrict__ wsP, float* __restrict__ wsA,
    float* __restrict__ wsZ, float* __restrict__ wsCnt,
    unsigned int* __restrict__ counter,
    float* __restrict__ out, int B, int K)
{
    const int b    = blockIdx.x / SPLIT;
    const int s    = blockIdx.x % SPLIT;
    const int t    = threadIdx.x;
    const int lane = t & 63;
    const int wv   = t >> 6;                // 0..3
    const int row0 = s * RPB + wv * RW;     // wave's first row (contiguous)
    const int nblk = B * SPLIT;

    __shared__ float ldsP[4][PD];           // 16 KB
    __shared__ float ldsA[4][PD];           // 16 KB
    __shared__ int   cntLds;
    __shared__ int   lastFlag;
    __shared__ float red[K4];

    // ---------------- Phase A: stream + normalize + accumulate -------------
    float accP[16], accA[16];
#pragma unroll
    for (int i = 0; i < 16; ++i) { accP[i] = 0.f; accA[i] = 0.f; }
    int cnt = 0;

    const size_t growBase = (size_t)b * PER_IMG + row0;
    const float* rp = box + growBase * PD;

#pragma unroll 1
    for (int it = 0; it < RW; it += 4) {
        f32x4 v[4][4];
#pragma unroll
        for (int r = 0; r < 4; ++r)
#pragma unroll
            for (int j = 0; j < 4; ++j)
                v[r][j] = ntload4(rp + (size_t)(it + r) * PD + (j * 64 + lane) * 4);

        float iou[4];
#pragma unroll
        for (int r = 0; r < 4; ++r) iou[r] = ious[growBase + it + r];

        float ss[4];
#pragma unroll
        for (int r = 0; r < 4; ++r) {
            float acc = 0.f;
#pragma unroll
            for (int j = 0; j < 4; ++j)
                acc += v[r][j][0] * v[r][j][0] + v[r][j][1] * v[r][j][1]
                     + v[r][j][2] * v[r][j][2] + v[r][j][3] * v[r][j][3];
            ss[r] = acc;
        }
#pragma unroll
        for (int off = 32; off >= 1; off >>= 1) {
#pragma unroll
            for (int r = 0; r < 4; ++r)
                ss[r] += __shfl_xor(ss[r], off, 64);
        }

#pragma unroll
        for (int r = 0; r < 4; ++r) {
            const float inv = 1.0f / fmaxf(sqrtf(ss[r]), 1e-12f);
            const bool pos = iou[r] >= IOU_THRES;
            if (pos && lane == 0) ++cnt;
            const float pm = pos ? inv : 0.f;
#pragma unroll
            for (int j = 0; j < 4; ++j) {
#pragma unroll
                for (int c = 0; c < 4; ++c) {
                    accA[j * 4 + c] += v[r][j][c] * inv;
                    accP[j * 4 + c] += v[r][j][c] * pm;
                }
            }
        }
    }

    // ---- low-VGPR epilogue: each wave writes its LDS quadrant (R3 form) ---
    if (t == 0) { cntLds = 0; lastFlag = 0; }
#pragma unroll
    for (int j = 0; j < 4; ++j) {
        const int d = (j * 64 + lane) * 4;
        f32x4 p = { accP[j*4+0], accP[j*4+1], accP[j*4+2], accP[j*4+3] };
        f32x4 a = { accA[j*4+0], accA[j*4+1], accA[j*4+2], accA[j*4+3] };
        *reinterpret_cast<f32x4*>(&ldsP[wv][d]) = p;
        *reinterpret_cast<f32x4*>(&ldsA[wv][d]) = a;
    }
    __syncthreads();
    if (lane == 0 && cnt) atomicAdd(&cntLds, cnt);

    // ---- wave k: combine quadrants inline, dot against z[k,b] (L2-hot) ----
    if (wv < K4) {
        const float* zp = crop + ((size_t)wv * B + b) * PD;
        float dotP = 0.f, dotA = 0.f, ssz = 0.f;
#pragma unroll
        for (int j = 0; j < 4; ++j) {
            const int d = (j * 64 + lane) * 4;
            const f32x4 z  = *reinterpret_cast<const f32x4*>(zp + d);
            f32x4 sP = *reinterpret_cast<const f32x4*>(&ldsP[0][d]);
            f32x4 sA = *reinterpret_cast<const f32x4*>(&ldsA[0][d]);
#pragma unroll
            for (int w = 1; w < 4; ++w) {
                sP += *reinterpret_cast<const f32x4*>(&ldsP[w][d]);
                sA += *reinterpret_cast<const f32x4*>(&ldsA[w][d]);
            }
#pragma unroll
            for (int c = 0; c < 4; ++c) {
                dotP += sP[c] * z[c];
                dotA += sA[c] * z[c];
                ssz  += z[c]  * z[c];
            }
        }
#pragma unroll
        for (int off = 32; off >= 1; off >>= 1) {
            dotP += __shfl_xor(dotP, off, 64);
            dotA += __shfl_xor(dotA, off, 64);
            ssz  += __shfl_xor(ssz,  off, 64);
        }
        if (lane == 0) {
            const size_t kb = (size_t)wv * B + b;
            agstore(&wsP[kb * SPLIT + s], dotP);
            agstore(&wsA[kb * SPLIT + s], dotA);
            if (s == 0) agstore(&wsZ[kb], ssz);
        }
    }
    __syncthreads();   // per-wave vmcnt(0): ALL waves' sc1 stores drained here

    // -------- completion count: publish cnt, wait own store, relaxed add ---
    if (t == 0) {
        agstore(&wsCnt[b * SPLIT + s], (float)cntLds);
        asm volatile("s_waitcnt vmcnt(0)" ::: "memory");
        const unsigned old = __hip_atomic_fetch_add(
            counter, 1u, __ATOMIC_RELAXED, __HIP_MEMORY_SCOPE_AGENT);
        if (old == (unsigned)(nblk - 1)) lastFlag = 1;
    }
    __syncthreads();
    if (!lastFlag) return;

    // ---------------- Phase B: final reduction (last block only) -----------
    float* spl = &ldsP[0][0];               // reuse quadrant LDS (K*B <= 512)
    const int KB = K4 * B;
    for (int pair = t; pair < KB; pair += 256) {
        const int bb = pair & (B - 1);
        float P = 0.f, A = 0.f, C = 0.f;
#pragma unroll
        for (int sp = 0; sp < SPLIT; ++sp) {
            P += agload(&wsP[(size_t)pair * SPLIT + sp]);
            A += agload(&wsA[(size_t)pair * SPLIT + sp]);
            C += agload(&wsCnt[bb * SPLIT + sp]);
        }
        const float invz = 1.0f / fmaxf(sqrtf(agload(&wsZ[pair])), 1e-12f);
        const float simP = -(P * invz) / C;
        const float simN = -((A - P) * invz) / ((float)PER_IMG - C);
        const float x = (simN - simP) * TEMP_INV;
        spl[pair] = fmaxf(x, 0.f) + log1pf(expf(-fabsf(x)));  // softplus
    }
    __syncthreads();

    if (wv < K4) {
        float v = 0.f;
        for (int bb = lane; bb < B; bb += 64) v += spl[wv * B + bb];
#pragma unroll
        for (int off = 32; off >= 1; off >>= 1)
            v += __shfl_xor(v, off, 64);
        if (lane == 0) red[wv] = v;
    }
    __syncthreads();
    if (t == 0) {
        float m = red[0];
        for (int k = 1; k < K4; ++k) m = fminf(m, red[k]);
        out[0] = m / (float)B;
    }
}

// ---------------------------------------------------------------------------
extern "C" void kernel_launch(void* const* d_in, const int* in_sizes, int n_in,
                              void* d_out, int out_size, void* d_ws, size_t ws_size,
                              hipStream_t stream)
{
    const float* box  = (const float*)d_in[0];   // [N, D] f32
    const float* crop = (const float*)d_in[1];   // [K, B, D] f32
    const float* ious = (const float*)d_in[3];   // [N] f32

    const int N = in_sizes[3];
    const int B = N / PER_IMG;                   // 128
    const int D = in_sizes[0] / N;               // 1024 (layout fixed = PD)
    const int K = in_sizes[1] / (B * D);         // 4 (problem-fixed = K4)

    char* w = (char*)d_ws;
    float* wsP   = (float*)w;  w += (size_t)K4 * B * SPLIT * sizeof(float);
    float* wsA   = (float*)w;  w += (size_t)K4 * B * SPLIT * sizeof(float);
    float* wsZ   = (float*)w;  w += (size_t)K4 * B * sizeof(float);
    float* wsCnt = (float*)w;  w += (size_t)B * SPLIT * sizeof(float);
    unsigned int* counter = (unsigned int*)w;

    hipLaunchKernelGGL(k0_init, dim3(1), dim3(64), 0, stream, counter);
    hipLaunchKernelGGL(k1_fused, dim3(B * SPLIT), dim3(256), 0, stream,
                       box, ious, crop, wsP, wsA, wsZ, wsCnt, counter,
                       (float*)d_out, B, K);
}

// Round 7
// 33.085 us; speedup vs baseline: 1.8487x; 1.4307x over previous
//
#include <hip/hip_runtime.h>
#include <cstdint>
#include <cstddef>

#define PD 1024          // feature dim D (fixed by the problem)
#define PER_IMG 256      // proposals per image
#define TEMP_INV 5.0f    // 1 / TEMPERATURE (0.2)
#define IOU_THRES 0.4f
#define SPLIT 16         // blocks per image (R7: 8 -> 16 for +TLP)
#define RPB (PER_IMG / SPLIT)   // rows per block  = 16
#define RW  (RPB / 4)           // rows per wave   = 4
#define K4  4            // K scales (problem-fixed)

typedef float f32x4 __attribute__((ext_vector_type(4)));

__device__ inline f32x4 ntload4(const float* p) {
    return __builtin_nontemporal_load(reinterpret_cast<const f32x4*>(p));
}

// ---------------------------------------------------------------------------
// Kernel 1 (R3 structure): block (b,s) normalizes rows [s*RPB,(s+1)*RPB) of
// image b, accumulates masked row-sums in registers, LDS quadrant-combine,
// then wave k dots the combined sums against z[k,b] (crop is L2-hot).
// Emits 2K+1(+K) scalars per block via ordinary stores (kernel-boundary
// release/acquire makes them visible to k2 — no fences, the R4 lesson).
// ---------------------------------------------------------------------------
__global__ __launch_bounds__(256) void k1_rowsum(
    const float* __restrict__ box, const float* __restrict__ ious,
    const float* __restrict__ crop,
    float* __restrict__ wsP, float* __restrict__ wsA,
    float* __restrict__ wsZ, float* __restrict__ wsCnt, int B, int K)
{
    const int b    = blockIdx.x / SPLIT;
    const int s    = blockIdx.x % SPLIT;
    const int t    = threadIdx.x;
    const int lane = t & 63;
    const int wv   = t >> 6;                // 0..3
    const int row0 = s * RPB + wv * RW;     // wave's first row (contiguous)

    __shared__ float ldsP[4][PD];           // 16 KB
    __shared__ float ldsA[4][PD];           // 16 KB
    __shared__ int   cntLds;

    float accP[16], accA[16];
#pragma unroll
    for (int i = 0; i < 16; ++i) { accP[i] = 0.f; accA[i] = 0.f; }
    int cnt = 0;

    const size_t growBase = (size_t)b * PER_IMG + row0;
    const float* rp = box + growBase * PD;

    // ---- single batch: RW=4 rows, 16 nontemporal float4 loads in flight ---
    {
        f32x4 v[4][4];
#pragma unroll
        for (int r = 0; r < 4; ++r)
#pragma unroll
            for (int j = 0; j < 4; ++j)
                v[r][j] = ntload4(rp + (size_t)r * PD + (j * 64 + lane) * 4);

        float iou[4];
#pragma unroll
        for (int r = 0; r < 4; ++r) iou[r] = ious[growBase + r];

        float ss[4];
#pragma unroll
        for (int r = 0; r < 4; ++r) {
            float acc = 0.f;
#pragma unroll
            for (int j = 0; j < 4; ++j)
                acc += v[r][j][0] * v[r][j][0] + v[r][j][1] * v[r][j][1]
                     + v[r][j][2] * v[r][j][2] + v[r][j][3] * v[r][j][3];
            ss[r] = acc;
        }
#pragma unroll
        for (int off = 32; off >= 1; off >>= 1) {
#pragma unroll
            for (int r = 0; r < 4; ++r)
                ss[r] += __shfl_xor(ss[r], off, 64);
        }

#pragma unroll
        for (int r = 0; r < 4; ++r) {
            const float inv = 1.0f / fmaxf(sqrtf(ss[r]), 1e-12f);
            const bool pos = iou[r] >= IOU_THRES;
            if (pos && lane == 0) ++cnt;
            const float pm = pos ? inv : 0.f;
#pragma unroll
            for (int j = 0; j < 4; ++j) {
#pragma unroll
                for (int c = 0; c < 4; ++c) {
                    accA[j * 4 + c] += v[r][j][c] * inv;
                    accP[j * 4 + c] += v[r][j][c] * pm;
                }
            }
        }
    }

    // ---- each wave writes its LDS quadrant -------------------------------
    if (t == 0) cntLds = 0;
#pragma unroll
    for (int j = 0; j < 4; ++j) {
        const int d = (j * 64 + lane) * 4;
        f32x4 p = { accP[j*4+0], accP[j*4+1], accP[j*4+2], accP[j*4+3] };
        f32x4 a = { accA[j*4+0], accA[j*4+1], accA[j*4+2], accA[j*4+3] };
        *reinterpret_cast<f32x4*>(&ldsP[wv][d]) = p;
        *reinterpret_cast<f32x4*>(&ldsA[wv][d]) = a;
    }
    __syncthreads();
    if (lane == 0 && cnt) atomicAdd(&cntLds, cnt);

    // ---- wave k: combine quadrants inline, dot against z[k,b] (L2-hot) ----
    if (wv < K4) {
        const float* zp = crop + ((size_t)wv * B + b) * PD;
        float dotP = 0.f, dotA = 0.f, ssz = 0.f;
#pragma unroll
        for (int j = 0; j < 4; ++j) {
            const int d = (j * 64 + lane) * 4;
            const f32x4 z  = *reinterpret_cast<const f32x4*>(zp + d);
            f32x4 sP = *reinterpret_cast<const f32x4*>(&ldsP[0][d]);
            f32x4 sA = *reinterpret_cast<const f32x4*>(&ldsA[0][d]);
#pragma unroll
            for (int w = 1; w < 4; ++w) {
                sP += *reinterpret_cast<const f32x4*>(&ldsP[w][d]);
                sA += *reinterpret_cast<const f32x4*>(&ldsA[w][d]);
            }
#pragma unroll
            for (int c = 0; c < 4; ++c) {
                dotP += sP[c] * z[c];
                dotA += sA[c] * z[c];
                ssz  += z[c]  * z[c];
            }
        }
#pragma unroll
        for (int off = 32; off >= 1; off >>= 1) {
            dotP += __shfl_xor(dotP, off, 64);
            dotA += __shfl_xor(dotA, off, 64);
            ssz  += __shfl_xor(ssz,  off, 64);
        }
        if (lane == 0) {
            const size_t kb = (size_t)wv * B + b;
            wsP[kb * SPLIT + s] = dotP;
            wsA[kb * SPLIT + s] = dotA;
            if (s == 0) wsZ[kb] = ssz;
        }
    }
    __syncthreads();
    if (t == 0) wsCnt[b * SPLIT + s] = (float)cntLds;
}

// ---------------------------------------------------------------------------
// Kernel 2: combine SPLIT partials -> softplus per (k,b) -> sum_b -> min_k.
// One block, 256 threads; input ~74 KB, partial rows are 16 consecutive
// floats -> f32x4 loads.
// ---------------------------------------------------------------------------
__global__ __launch_bounds__(256) void k2_final(
    const float* __restrict__ wsP, const float* __restrict__ wsA,
    const float* __restrict__ wsZ, const float* __restrict__ wsCnt,
    float* __restrict__ out, int B, int K)
{
    const int t    = threadIdx.x;
    const int lane = t & 63;
    const int wv   = t >> 6;

    __shared__ float spl[512];      // K*B <= 512
    __shared__ float red[K4];

    const int KB = K4 * B;
    for (int pair = t; pair < KB; pair += 256) {
        const int bb = pair & (B - 1);
        f32x4 P4 = {0.f,0.f,0.f,0.f}, A4 = P4, C4 = P4;
#pragma unroll
        for (int g = 0; g < SPLIT / 4; ++g) {
            P4 += *reinterpret_cast<const f32x4*>(&wsP[(size_t)pair * SPLIT + g * 4]);
            A4 += *reinterpret_cast<const f32x4*>(&wsA[(size_t)pair * SPLIT + g * 4]);
            C4 += *reinterpret_cast<const f32x4*>(&wsCnt[(size_t)bb * SPLIT + g * 4]);
        }
        const float P = P4[0] + P4[1] + P4[2] + P4[3];
        const float A = A4[0] + A4[1] + A4[2] + A4[3];
        const float C = C4[0] + C4[1] + C4[2] + C4[3];
        const float invz = 1.0f / fmaxf(sqrtf(wsZ[pair]), 1e-12f);
        const float simP = -(P * invz) / C;
        const float simN = -((A - P) * invz) / ((float)PER_IMG - C);
        const float x = (simN - simP) * TEMP_INV;
        spl[pair] = fmaxf(x, 0.f) + log1pf(expf(-fabsf(x)));  // softplus
    }
    __syncthreads();

    if (wv < K4) {
        float v = 0.f;
        for (int bb = lane; bb < B; bb += 64) v += spl[wv * B + bb];
#pragma unroll
        for (int off = 32; off >= 1; off >>= 1)
            v += __shfl_xor(v, off, 64);
        if (lane == 0) red[wv] = v;
    }
    __syncthreads();
    if (t == 0) {
        float m = red[0];
        for (int k = 1; k < K4; ++k) m = fminf(m, red[k]);
        out[0] = m / (float)B;
    }
}

// ---------------------------------------------------------------------------
extern "C" void kernel_launch(void* const* d_in, const int* in_sizes, int n_in,
                              void* d_out, int out_size, void* d_ws, size_t ws_size,
                              hipStream_t stream)
{
    const float* box  = (const float*)d_in[0];   // [N, D] f32
    const float* crop = (const float*)d_in[1];   // [K, B, D] f32
    const float* ious = (const float*)d_in[3];   // [N] f32

    const int N = in_sizes[3];
    const int B = N / PER_IMG;                   // 128
    const int D = in_sizes[0] / N;               // 1024 (layout fixed = PD)
    const int K = in_sizes[1] / (B * D);         // 4 (problem-fixed = K4)

    char* w = (char*)d_ws;
    float* wsP   = (float*)w;  w += (size_t)K4 * B * SPLIT * sizeof(float);
    float* wsA   = (float*)w;  w += (size_t)K4 * B * SPLIT * sizeof(float);
    float* wsZ   = (float*)w;  w += (size_t)K4 * B * sizeof(float);
    float* wsCnt = (float*)w;

    hipLaunchKernelGGL(k1_rowsum, dim3(B * SPLIT), dim3(256), 0, stream,
                       box, ious, crop, wsP, wsA, wsZ, wsCnt, B, K);
    hipLaunchKernelGGL(k2_final, dim3(1), dim3(256), 0, stream,
                       wsP, wsA, wsZ, wsCnt, (float*)d_out, B, K);
}

// Round 8
// 29.877 us; speedup vs baseline: 2.0472x; 1.1073x over previous
//
#include <hip/hip_runtime.h>
#include <cstdint>
#include <cstddef>

#define PD 1024          // feature dim D (fixed by the problem)
#define PER_IMG 256      // proposals per image
#define TEMP_INV 5.0f    // 1 / TEMPERATURE (0.2)
#define IOU_THRES 0.4f
#define SPLIT 8          // blocks per image (R7 lesson: 16 regresses)
#define RPB (PER_IMG / SPLIT)   // rows per block  = 32
#define RW  (RPB / 4)           // rows per wave   = 8
#define K4  4            // K scales (problem-fixed)

typedef float f32x4 __attribute__((ext_vector_type(4)));

__device__ inline f32x4 ntload4(const float* p) {
    return __builtin_nontemporal_load(reinterpret_cast<const f32x4*>(p));
}

// ---------------------------------------------------------------------------
// Kernel 1 (R3 structure + XCD-affinity swizzle): block (b,s) normalizes rows
// [s*RPB,(s+1)*RPB) of image b, accumulates masked row-sums in registers,
// LDS quadrant-combine, then wave k dots the combined sums against z[k,b].
//
// Swizzle: dispatch round-robins consecutive ids across the 8 XCDs
// (XCD = id%8). Mapping b=(id&7)+8*(id>>6), s=(id>>3)&7 puts all 8 split-
// blocks of image b on XCD b%8 -> each image's 16 KB of crop is fetched by
// exactly one XCD (2 MB total HBM crop fetch instead of ~16 MB), and the
// z-vectors are L2-hot for every block that needs them. Bijective on [0,1024).
// Perf heuristic only — correctness never depends on placement (G16).
// ---------------------------------------------------------------------------
__global__ __launch_bounds__(256) void k1_rowsum(
    const float* __restrict__ box, const float* __restrict__ ious,
    const float* __restrict__ crop,
    float* __restrict__ wsP, float* __restrict__ wsA,
    float* __restrict__ wsZ, float* __restrict__ wsCnt, int B, int K)
{
    const int id   = blockIdx.x;
    const int b    = (id & 7) + 8 * (id >> 6);   // image index
    const int s    = (id >> 3) & 7;              // split index
    const int t    = threadIdx.x;
    const int lane = t & 63;
    const int wv   = t >> 6;                // 0..3
    const int row0 = s * RPB + wv * RW;     // wave's first row (contiguous)

    __shared__ float ldsP[4][PD];           // 16 KB
    __shared__ float ldsA[4][PD];           // 16 KB
    __shared__ int   cntLds;

    float accP[16], accA[16];
#pragma unroll
    for (int i = 0; i < 16; ++i) { accP[i] = 0.f; accA[i] = 0.f; }
    int cnt = 0;

    const size_t growBase = (size_t)b * PER_IMG + row0;
    const float* rp = box + growBase * PD;

#pragma unroll 1
    for (int it = 0; it < RW; it += 4) {
        f32x4 v[4][4];
#pragma unroll
        for (int r = 0; r < 4; ++r)
#pragma unroll
            for (int j = 0; j < 4; ++j)
                v[r][j] = ntload4(rp + (size_t)(it + r) * PD + (j * 64 + lane) * 4);

        float iou[4];
#pragma unroll
        for (int r = 0; r < 4; ++r) iou[r] = ious[growBase + it + r];

        float ss[4];
#pragma unroll
        for (int r = 0; r < 4; ++r) {
            float acc = 0.f;
#pragma unroll
            for (int j = 0; j < 4; ++j)
                acc += v[r][j][0] * v[r][j][0] + v[r][j][1] * v[r][j][1]
                     + v[r][j][2] * v[r][j][2] + v[r][j][3] * v[r][j][3];
            ss[r] = acc;
        }
#pragma unroll
        for (int off = 32; off >= 1; off >>= 1) {
#pragma unroll
            for (int r = 0; r < 4; ++r)
                ss[r] += __shfl_xor(ss[r], off, 64);
        }

#pragma unroll
        for (int r = 0; r < 4; ++r) {
            const float inv = 1.0f / fmaxf(sqrtf(ss[r]), 1e-12f);
            const bool pos = iou[r] >= IOU_THRES;
            if (pos && lane == 0) ++cnt;
            const float pm = pos ? inv : 0.f;
#pragma unroll
            for (int j = 0; j < 4; ++j) {
#pragma unroll
                for (int c = 0; c < 4; ++c) {
                    accA[j * 4 + c] += v[r][j][c] * inv;
                    accP[j * 4 + c] += v[r][j][c] * pm;
                }
            }
        }
    }

    // ---- each wave writes its LDS quadrant -------------------------------
    if (t == 0) cntLds = 0;
#pragma unroll
    for (int j = 0; j < 4; ++j) {
        const int d = (j * 64 + lane) * 4;
        f32x4 p = { accP[j*4+0], accP[j*4+1], accP[j*4+2], accP[j*4+3] };
        f32x4 a = { accA[j*4+0], accA[j*4+1], accA[j*4+2], accA[j*4+3] };
        *reinterpret_cast<f32x4*>(&ldsP[wv][d]) = p;
        *reinterpret_cast<f32x4*>(&ldsA[wv][d]) = a;
    }
    __syncthreads();
    if (lane == 0 && cnt) atomicAdd(&cntLds, cnt);

    // ---- wave k: combine quadrants inline, dot against z[k,b] (L2-hot) ----
    if (wv < K4) {
        const float* zp = crop + ((size_t)wv * B + b) * PD;
        float dotP = 0.f, dotA = 0.f, ssz = 0.f;
#pragma unroll
        for (int j = 0; j < 4; ++j) {
            const int d = (j * 64 + lane) * 4;
            const f32x4 z  = *reinterpret_cast<const f32x4*>(zp + d);
            f32x4 sP = *reinterpret_cast<const f32x4*>(&ldsP[0][d]);
            f32x4 sA = *reinterpret_cast<const f32x4*>(&ldsA[0][d]);
#pragma unroll
            for (int w = 1; w < 4; ++w) {
                sP += *reinterpret_cast<const f32x4*>(&ldsP[w][d]);
                sA += *reinterpret_cast<const f32x4*>(&ldsA[w][d]);
            }
#pragma unroll
            for (int c = 0; c < 4; ++c) {
                dotP += sP[c] * z[c];
                dotA += sA[c] * z[c];
                ssz  += z[c]  * z[c];
            }
        }
#pragma unroll
        for (int off = 32; off >= 1; off >>= 1) {
            dotP += __shfl_xor(dotP, off, 64);
            dotA += __shfl_xor(dotA, off, 64);
            ssz  += __shfl_xor(ssz,  off, 64);
        }
        if (lane == 0) {
            const size_t kb = (size_t)wv * B + b;
            wsP[kb * SPLIT + s] = dotP;
            wsA[kb * SPLIT + s] = dotA;
            if (s == 0) wsZ[kb] = ssz;
        }
    }
    __syncthreads();
    if (t == 0) wsCnt[b * SPLIT + s] = (float)cntLds;
}

// ---------------------------------------------------------------------------
// Kernel 2: combine SPLIT partials -> softplus per (k,b) -> sum_b -> min_k.
// One block, 256 threads; input ~40 KB, f32x4-vectorized combine.
// ---------------------------------------------------------------------------
__global__ __launch_bounds__(256) void k2_final(
    const float* __restrict__ wsP, const float* __restrict__ wsA,
    const float* __restrict__ wsZ, const float* __restrict__ wsCnt,
    float* __restrict__ out, int B, int K)
{
    const int t    = threadIdx.x;
    const int lane = t & 63;
    const int wv   = t >> 6;

    __shared__ float spl[512];      // K*B <= 512
    __shared__ float red[K4];

    const int KB = K4 * B;
    for (int pair = t; pair < KB; pair += 256) {
        const int bb = pair & (B - 1);
        f32x4 P4 = {0.f,0.f,0.f,0.f}, A4 = P4, C4 = P4;
#pragma unroll
        for (int g = 0; g < SPLIT / 4; ++g) {
            P4 += *reinterpret_cast<const f32x4*>(&wsP[(size_t)pair * SPLIT + g * 4]);
            A4 += *reinterpret_cast<const f32x4*>(&wsA[(size_t)pair * SPLIT + g * 4]);
            C4 += *reinterpret_cast<const f32x4*>(&wsCnt[(size_t)bb * SPLIT + g * 4]);
        }
        const float P = P4[0] + P4[1] + P4[2] + P4[3];
        const float A = A4[0] + A4[1] + A4[2] + A4[3];
        const float C = C4[0] + C4[1] + C4[2] + C4[3];
        const float invz = 1.0f / fmaxf(sqrtf(wsZ[pair]), 1e-12f);
        const float simP = -(P * invz) / C;
        const float simN = -((A - P) * invz) / ((float)PER_IMG - C);
        const float x = (simN - simP) * TEMP_INV;
        spl[pair] = fmaxf(x, 0.f) + log1pf(expf(-fabsf(x)));  // softplus
    }
    __syncthreads();

    if (wv < K4) {
        float v = 0.f;
        for (int bb = lane; bb < B; bb += 64) v += spl[wv * B + bb];
#pragma unroll
        for (int off = 32; off >= 1; off >>= 1)
            v += __shfl_xor(v, off, 64);
        if (lane == 0) red[wv] = v;
    }
    __syncthreads();
    if (t == 0) {
        float m = red[0];
        for (int k = 1; k < K4; ++k) m = fminf(m, red[k]);
        out[0] = m / (float)B;
    }
}

// ---------------------------------------------------------------------------
extern "C" void kernel_launch(void* const* d_in, const int* in_sizes, int n_in,
                              void* d_out, int out_size, void* d_ws, size_t ws_size,
                              hipStream_t stream)
{
    const float* box  = (const float*)d_in[0];   // [N, D] f32
    const float* crop = (const float*)d_in[1];   // [K, B, D] f32
    const float* ious = (const float*)d_in[3];   // [N] f32

    const int N = in_sizes[3];
    const int B = N / PER_IMG;                   // 128
    const int D = in_sizes[0] / N;               // 1024 (layout fixed = PD)
    const int K = in_sizes[1] / (B * D);         // 4 (problem-fixed = K4)

    char* w = (char*)d_ws;
    float* wsP   = (float*)w;  w += (size_t)K4 * B * SPLIT * sizeof(float);
    float* wsA   = (float*)w;  w += (size_t)K4 * B * SPLIT * sizeof(float);
    float* wsZ   = (float*)w;  w += (size_t)K4 * B * sizeof(float);
    float* wsCnt = (float*)w;

    hipLaunchKernelGGL(k1_rowsum, dim3(B * SPLIT), dim3(256), 0, stream,
                       box, ious, crop, wsP, wsA, wsZ, wsCnt, B, K);
    hipLaunchKernelGGL(k2_final, dim3(1), dim3(256), 0, stream,
                       wsP, wsA, wsZ, wsCnt, (float*)d_out, B, K);
}